// Round 15
// baseline (495.133 us; speedup 1.0000x reference)
//
#include <hip/hip_runtime.h>
#include <stdint.h>

#define LSEQ 2048
#define M_TOT 32768          // B*L
#define KDIM 2048            // 2H
#define NKT 64               // K tiles of 32
#define NCT 4                // col tiles of 256
#define NEG_INF_F (-10000000000.0f)

typedef _Float16 f16;
typedef f16 f16x8 __attribute__((ext_vector_type(8)));
typedef float f32x4 __attribute__((ext_vector_type(4)));

// ---------------- ws layout ----------------
// [0, 64K)      sdec f32[16][1024]
// [64K, 576K)   part f32[4][32768]
// [2M, 6M)      weT  tiled fp16 B [4 ct][64 kt][1024 granules x 16B]
#define WS_SDEC_OFF  0
#define WS_PART_OFF  (64u << 10)
#define WS_WET_OFF   (2u << 20)

// LDS: A 3 slots x 16KB + B 4 slots x 16KB = 112KB
#define A_OFF(s) ((s) * 16384)
#define B_OFF(s) (49152 + (s) * 16384)

__device__ inline void gload16(const void* g, void* l) {
    __builtin_amdgcn_global_load_lds(
        (const __attribute__((address_space(1))) void*)g,
        (__attribute__((address_space(3))) void*)l, 16, 0, 0);
}

// fast tanh(x)*s with sign fold
__device__ inline float tanh_mul(float x, float s) {
    float ax = __builtin_fabsf(x);
    float e  = __expf(-2.f * ax);
    float th = (1.f - e) * __builtin_amdgcn_rcpf(1.f + e);
    float sv = __uint_as_float(__float_as_uint(s) ^ (__float_as_uint(x) & 0x80000000u));
    return th * sv;
}

// W_e -> tiled fp16 B, 0-conflict swizzle (r5-verified): granule g: ct=g>>16,
// kt=(g>>10)&63, p=g&1023, row=p>>2, sl=(p&3)^((row>>1)&3).
__global__ __launch_bounds__(256) void wecvt_tiled(const float* __restrict__ attn_w,
                                                   f16* __restrict__ weT) {
    int g = blockIdx.x * 1024 + threadIdx.x;
    #pragma unroll
    for (int q = 0; q < 4; ++q, g += 256) {
        int ct  = g >> 16;
        int rem = g & 65535;
        int kt  = rem >> 10;
        int p   = rem & 1023;
        int row = p >> 2;
        int sl  = (p & 3) ^ ((row >> 1) & 3);
        const float* s = attn_w + (size_t)(ct * 256 + row) * 3072 + 1024 + kt * 32 + sl * 8;
        float4 a = *(const float4*)s;
        float4 b = *(const float4*)(s + 4);
        f16x8 h = { (f16)a.x,(f16)a.y,(f16)a.z,(f16)a.w,(f16)b.x,(f16)b.y,(f16)b.z,(f16)b.w };
        *(f16x8*)(weT + (size_t)g * 8) = h;
    }
}

// score_dec[b][h] = attn_b[h] + sum_k v[b][k] * attn_w[h][k]
__global__ void sdec_kernel(const float* __restrict__ v,
                            const float* __restrict__ attn_w,
                            const float* __restrict__ attn_b,
                            float* __restrict__ sdec) {
    int gid  = blockIdx.x * 4 + (threadIdx.x >> 6);
    int lane = threadIdx.x & 63;
    int b = gid >> 10;
    int h = gid & 1023;
    const float* vr = v + b * 1024;
    const float* wr = attn_w + (size_t)h * 3072;
    float s = 0.f;
    #pragma unroll 4
    for (int k = lane; k < 1024; k += 64) s += vr[k] * wr[k];
    #pragma unroll
    for (int m = 1; m < 64; m <<= 1) s += __shfl_xor(s, m);
    if (lane == 0) sdec[b * 1024 + h] = s + attn_b[h];
}

// ONE-PASS GEMM with cross-iteration fragment read-ahead.
// 256x256 tile, 8 waves (2M x 4N), BK=32, 1 block/CU, ONE barrier per K-tile.
// iter t: {ds_read frags(t+1) || writeA(t+2) || loadAreg/stageB(t+3)} ;
//         32 MFMA on frags(t) [compiler-counted lgkm wait drains only old reads];
//         counted vmcnt(6); s_barrier.
// A ring 3 slots, B ring 4 slots (distances derived so every slot rewrite
// happens after the previous tenant's reads are counter-drained).
__global__ __launch_bounds__(512, 2) void fused_gemm(
        const float* __restrict__ enc,  // [32768][2048] fp32
        const f16* __restrict__ weT,    // [4 ct][64 kt][16KB]
        const float* __restrict__ sdec, // [16][1024]
        const float* __restrict__ vw,   // [1024]
        float* __restrict__ part)       // [NCT][32768]
{
    // chunked XCD remap: 512 blocks, 64/XCD; 4 ct-siblings of one rt adjacent
    const int logical = ((int)blockIdx.x & 7) * 64 + ((int)blockIdx.x >> 3);
    const int rt = logical >> 2;
    const int ct = logical & 3;

    const int tid = threadIdx.x;
    const int l15 = tid & 15;
    const int l4  = (tid >> 4) & 3;
    const int wv  = tid >> 6;        // 0..7
    const int wm  = wv >> 2;         // 0..1  (128 rows each)
    const int wn  = wv & 3;          // 0..3  (64 cols each)

    __shared__ char lds[114688];     // A 3x16KB + B 4x16KB
    __shared__ float red[4][256];

    const int rowbase = rt * 256;
    const char* bT = (const char*)weT + ((size_t)ct << 20);

    // ---- A staging: thread -> row ar=tid>>1, k-half ah=tid&1 (16 floats) ----
    const int ar_ = tid >> 1;
    const int ah  = tid & 1;
    const float* aG = enc + (size_t)(rowbase + ar_) * KDIM + ah * 16;
    const int aswz = (ar_ >> 1) & 3;
    const int awb0 = ar_ * 64 + (((2 * ah)     ^ aswz) << 4);
    const int awb1 = ar_ * 64 + (((2 * ah + 1) ^ aswz) << 4);

    // ---- frag reads (r5-verified 0-conflict): row 64B, phys = l4^((row>>1)&3)
    const int fswz = (l4 ^ ((l15 >> 1) & 3)) << 4;
    const int aro = (wm * 128 + l15) * 64 + fswz;   // + i*1024, i=0..7
    const int bro = (wn * 64  + l15) * 64 + fswz;   // + j*1024, j=0..3

    f32x4 acc[8][4] = {};

    auto loadAreg = [&](float4 (&s)[4], int t) {
        const float* p = aG + (size_t)t * 32;
        s[0] = *(const float4*)(p);
        s[1] = *(const float4*)(p + 4);
        s[2] = *(const float4*)(p + 8);
        s[3] = *(const float4*)(p + 12);
    };
    auto writeA = [&](const float4 (&s)[4], int slot) {
        char* d = lds + A_OFF(slot);
        auto c0 = __builtin_amdgcn_cvt_pkrtz(s[0].x, s[0].y);
        auto c1 = __builtin_amdgcn_cvt_pkrtz(s[0].z, s[0].w);
        auto c2 = __builtin_amdgcn_cvt_pkrtz(s[1].x, s[1].y);
        auto c3 = __builtin_amdgcn_cvt_pkrtz(s[1].z, s[1].w);
        auto c4 = __builtin_amdgcn_cvt_pkrtz(s[2].x, s[2].y);
        auto c5 = __builtin_amdgcn_cvt_pkrtz(s[2].z, s[2].w);
        auto c6 = __builtin_amdgcn_cvt_pkrtz(s[3].x, s[3].y);
        auto c7 = __builtin_amdgcn_cvt_pkrtz(s[3].z, s[3].w);
        f16x8 h0 = { (f16)c0[0],(f16)c0[1],(f16)c1[0],(f16)c1[1],
                     (f16)c2[0],(f16)c2[1],(f16)c3[0],(f16)c3[1] };
        f16x8 h1 = { (f16)c4[0],(f16)c4[1],(f16)c5[0],(f16)c5[1],
                     (f16)c6[0],(f16)c6[1],(f16)c7[0],(f16)c7[1] };
        *(f16x8*)(d + awb0) = h0;
        *(f16x8*)(d + awb1) = h1;
    };
    auto stageB = [&](int t, int slot) {
        const char* s = bT + ((size_t)t << 14) + tid * 16;
        char* d = lds + B_OFF(slot) + tid * 16;
        gload16(s, d); gload16(s + 8192, d + 8192);
    };
    auto readFr = [&](f16x8 (&fa)[8], f16x8 (&bf)[4], int aS, int bS) {
        const char* sa = lds + A_OFF(aS);
        const char* sb = lds + B_OFF(bS);
        #pragma unroll
        for (int ii = 0; ii < 8; ++ii) fa[ii] = *(const f16x8*)(sa + aro + ii * 1024);
        #pragma unroll
        for (int j = 0; j < 4; ++j)  bf[j] = *(const f16x8*)(sb + bro + j * 1024);
    };

    f16x8 faE[8], bfE[4], faO[8], bfO[4];
    float4 sE[4], sO[4];
    int aRd = 1, bRd = 1, aWr = 2, bWr = 3;

    auto body = [&](int t, f16x8 (&faN)[8], f16x8 (&bfN)[4],
                    f16x8 (&faC)[8], f16x8 (&bfC)[4],
                    float4 (&sWr)[4], float4 (&sLd)[4]) {
        if (t + 1 < NKT) readFr(faN, bfN, aRd, bRd);   // tile t+1 (slot written iter t-1)
        if (t + 2 < NKT) writeA(sWr, aWr);             // tile t+2 (regs loaded iter t-1)
        if (t + 3 < NKT) { loadAreg(sLd, t + 3); stageB(t + 3, bWr); }
        __builtin_amdgcn_s_setprio(1);
        #pragma unroll
        for (int ii = 0; ii < 8; ++ii)
            #pragma unroll
            for (int j = 0; j < 4; ++j)
                acc[ii][j] = __builtin_amdgcn_mfma_f32_16x16x32_f16(faC[ii], bfC[j], acc[ii][j], 0, 0, 0);
        __builtin_amdgcn_s_setprio(0);
        if (t < NKT - 4) { asm volatile("s_waitcnt vmcnt(6)" ::: "memory"); }
        else             { asm volatile("s_waitcnt vmcnt(0)" ::: "memory"); }
        __builtin_amdgcn_s_barrier();
        __builtin_amdgcn_sched_barrier(0);
        aRd = (aRd == 2) ? 0 : aRd + 1;
        aWr = (aWr == 2) ? 0 : aWr + 1;
        bRd = (bRd == 3) ? 0 : bRd + 1;
        bWr = (bWr == 3) ? 0 : bWr + 1;
    };

    // ---- prologue: A tiles 0,1,2 -> slots 0,1,2; B 0,1,2 -> slots 0,1,2;
    //      tile-2 A-regs left in sO for body(0)'s writeA ----
    loadAreg(sE, 0);
    stageB(0, 0); stageB(1, 1); stageB(2, 2);
    writeA(sE, 0);
    loadAreg(sO, 1);
    writeA(sO, 1);
    loadAreg(sO, 2);
    asm volatile("s_waitcnt lgkmcnt(0)" ::: "memory");
    __builtin_amdgcn_s_barrier();
    __builtin_amdgcn_sched_barrier(0);
    readFr(faE, bfE, 0, 0);   // tile 0 fragments

    #pragma unroll 1
    for (int tt = 0; tt < NKT; tt += 2) {
        body(tt,     faO, bfO, faE, bfE, sO, sE);
        body(tt + 1, faE, bfE, faO, bfO, sE, sO);
    }

    // ---------------- epilogue ----------------
    // C/D frag: col = l15, row = l4*4 + q; global row = rowbase + wm*128 + i*16 + l4*4 + q
    const int colbase = ct * 256;
    const int bidx = rt >> 3;

    float sd[4], vs[4];
    #pragma unroll
    for (int j = 0; j < 4; ++j) {
        const int col = colbase + wn * 64 + j * 16 + l15;
        sd[j] = sdec[bidx * 1024 + col];
        vs[j] = vw[col];
    }
    float psum[8][4] = {};
    #pragma unroll
    for (int i = 0; i < 8; ++i)
        #pragma unroll
        for (int j = 0; j < 4; ++j)
            #pragma unroll
            for (int q = 0; q < 4; ++q)
                psum[i][q] += tanh_mul(acc[i][j][q] + sd[j], vs[j]);

    #pragma unroll
    for (int i = 0; i < 8; ++i)
        #pragma unroll
        for (int q = 0; q < 4; ++q) {
            float s = psum[i][q];
            s += __shfl_xor(s, 1); s += __shfl_xor(s, 2);
            s += __shfl_xor(s, 4); s += __shfl_xor(s, 8);
            psum[i][q] = s;
        }

    __syncthreads();
    if (l15 == 0) {
        #pragma unroll
        for (int i = 0; i < 8; ++i)
            #pragma unroll
            for (int q = 0; q < 4; ++q)
                red[wn][wm * 128 + i * 16 + l4 * 4 + q] = psum[i][q];
    }
    __syncthreads();
    if (tid < 256)
        part[(size_t)ct * M_TOT + rowbase + tid] =
            red[0][tid] + red[1][tid] + red[2][tid] + red[3][tid];
}

// softmax over L per batch; mask==0 -> -1e10; sums the NCT partials.
__global__ __launch_bounds__(512) void softmax_kernel(
        const float* __restrict__ part, const int* __restrict__ mask,
        float* __restrict__ out) {
    int b = blockIdx.x;
    int tid = threadIdx.x;
    int lane = tid & 63, w = tid >> 6;
    __shared__ float sred[8];

    float vals[4];
    #pragma unroll
    for (int p = 0; p < 4; ++p) {
        int row = b * LSEQ + tid + p * 512;
        float val = 0.f;
        #pragma unroll
        for (int q = 0; q < NCT; ++q) val += part[(size_t)q * M_TOT + row];
        vals[p] = (mask[row] == 0) ? NEG_INF_F : val;
    }
    float mx = fmaxf(fmaxf(vals[0], vals[1]), fmaxf(vals[2], vals[3]));
    #pragma unroll
    for (int m = 1; m < 64; m <<= 1) mx = fmaxf(mx, __shfl_xor(mx, m));
    if (lane == 0) sred[w] = mx;
    __syncthreads();
    float gmax = sred[0];
    #pragma unroll
    for (int i = 1; i < 8; ++i) gmax = fmaxf(gmax, sred[i]);

    float es[4]; float ssum = 0.f;
    #pragma unroll
    for (int p = 0; p < 4; ++p) { es[p] = expf(vals[p] - gmax); ssum += es[p]; }
    #pragma unroll
    for (int m = 1; m < 64; m <<= 1) ssum += __shfl_xor(ssum, m);
    __syncthreads();
    if (lane == 0) sred[w] = ssum;
    __syncthreads();
    float gsum = 0.f;
    #pragma unroll
    for (int i = 0; i < 8; ++i) gsum += sred[i];
    float inv = 1.f / gsum;
    #pragma unroll
    for (int p = 0; p < 4; ++p)
        out[b * LSEQ + tid + p * 512] = es[p] * inv;
}

extern "C" void kernel_launch(void* const* d_in, const int* in_sizes, int n_in,
                              void* d_out, int out_size, void* d_ws, size_t ws_size,
                              hipStream_t stream) {
    const float* enc    = (const float*)d_in[0];
    const int*   mask   = (const int*)  d_in[1];
    const float* v      = (const float*)d_in[2];
    const float* attn_w = (const float*)d_in[3];
    const float* attn_b = (const float*)d_in[4];
    const float* v_w    = (const float*)d_in[5];
    float* out = (float*)d_out;

    char* ws = (char*)d_ws;
    float* sdec = (float*)(ws + WS_SDEC_OFF);
    float* part = (float*)(ws + WS_PART_OFF);
    f16*   weT  = (f16*)  (ws + WS_WET_OFF);

    hipLaunchKernelGGL(wecvt_tiled, dim3(256),  dim3(256), 0, stream, attn_w, weT);
    hipLaunchKernelGGL(sdec_kernel, dim3(4096), dim3(256), 0, stream, v, attn_w, attn_b, sdec);
    hipLaunchKernelGGL(fused_gemm,  dim3(512),  dim3(512), 0, stream,
                       enc, weT, sdec, v_w, part);
    hipLaunchKernelGGL(softmax_kernel, dim3(16), dim3(512), 0, stream, part, mask, out);
}

// Round 16
// 215.377 us; speedup vs baseline: 2.2989x; 2.2989x over previous
//
#include <hip/hip_runtime.h>
#include <stdint.h>

#define LSEQ 2048
#define M_TOT 32768          // B*L
#define KDIM 2048            // 2H
#define NKT 64               // K tiles of 32
#define NCT 4                // col tiles of 256
#define NEG_INF_F (-10000000000.0f)

typedef _Float16 f16;
typedef f16 f16x8 __attribute__((ext_vector_type(8)));
typedef float f32x4 __attribute__((ext_vector_type(4)));

// ---------------- ws layout ----------------
// [0, 64K)      sdec f32[16][1024]
// [64K, 576K)   part f32[4][32768]
// [2M, 6M)      weT  tiled fp16 B [4 ct][64 kt][1024 granules x 16B]
#define WS_SDEC_OFF  0
#define WS_PART_OFF  (64u << 10)
#define WS_WET_OFF   (2u << 20)

// LDS: A 3 slots x 16KB + B 3 slots x 16KB = 96KB
#define A_OFF(s) ((s) * 16384)
#define B_OFF(s) (49152 + (s) * 16384)

__device__ inline void gload16(const void* g, void* l) {
    __builtin_amdgcn_global_load_lds(
        (const __attribute__((address_space(1))) void*)g,
        (__attribute__((address_space(3))) void*)l, 16, 0, 0);
}

// fast tanh(x)*s with sign fold
__device__ inline float tanh_mul(float x, float s) {
    float ax = __builtin_fabsf(x);
    float e  = __expf(-2.f * ax);
    float th = (1.f - e) * __builtin_amdgcn_rcpf(1.f + e);
    float sv = __uint_as_float(__float_as_uint(s) ^ (__float_as_uint(x) & 0x80000000u));
    return th * sv;
}

// W_e -> tiled fp16 B, 0-conflict swizzle (r5-verified): granule g: ct=g>>16,
// kt=(g>>10)&63, p=g&1023, row=p>>2, sl=(p&3)^((row>>1)&3).
__global__ __launch_bounds__(256) void wecvt_tiled(const float* __restrict__ attn_w,
                                                   f16* __restrict__ weT) {
    int g = blockIdx.x * 1024 + threadIdx.x;
    #pragma unroll
    for (int q = 0; q < 4; ++q, g += 256) {
        int ct  = g >> 16;
        int rem = g & 65535;
        int kt  = rem >> 10;
        int p   = rem & 1023;
        int row = p >> 2;
        int sl  = (p & 3) ^ ((row >> 1) & 3);
        const float* s = attn_w + (size_t)(ct * 256 + row) * 3072 + 1024 + kt * 32 + sl * 8;
        float4 a = *(const float4*)s;
        float4 b = *(const float4*)(s + 4);
        f16x8 h = { (f16)a.x,(f16)a.y,(f16)a.z,(f16)a.w,(f16)b.x,(f16)b.y,(f16)b.z,(f16)b.w };
        *(f16x8*)(weT + (size_t)g * 8) = h;
    }
}

// score_dec[b][h] = attn_b[h] + sum_k v[b][k] * attn_w[h][k]
__global__ void sdec_kernel(const float* __restrict__ v,
                            const float* __restrict__ attn_w,
                            const float* __restrict__ attn_b,
                            float* __restrict__ sdec) {
    int gid  = blockIdx.x * 4 + (threadIdx.x >> 6);
    int lane = threadIdx.x & 63;
    int b = gid >> 10;
    int h = gid & 1023;
    const float* vr = v + b * 1024;
    const float* wr = attn_w + (size_t)h * 3072;
    float s = 0.f;
    #pragma unroll 4
    for (int k = lane; k < 1024; k += 64) s += vr[k] * wr[k];
    #pragma unroll
    for (int m = 1; m < 64; m <<= 1) s += __shfl_xor(s, m);
    if (lane == 0) sdec[b * 1024 + h] = s + attn_b[h];
}

// ONE-PASS GEMM, ONE barrier per K-tile, granular-lgkm overlap.
// 256x256 tile, 8 waves (2M x 4N), BK=32, 1 block/CU.
// iter t: {issue loadAreg(t+2); 12 ds_read frags(t); SB;
//          24 MFMA (trailing reads drain underneath);
//          writeA(t+2)+stageB(t+2) [auto-vmcnt stalls only this wave];
//          8 MFMA; lgkm0; counted vmcnt(2) [B(t+2) stays in flight]; barrier}.
// Rings: A 3 slots, B 3 slots -> write slot never equals read slot.
__global__ __launch_bounds__(512, 2) void fused_gemm(
        const float* __restrict__ enc,  // [32768][2048] fp32
        const f16* __restrict__ weT,    // [4 ct][64 kt][16KB]
        const float* __restrict__ sdec, // [16][1024]
        const float* __restrict__ vw,   // [1024]
        float* __restrict__ part)       // [NCT][32768]
{
    // chunked XCD remap: 512 blocks, 64/XCD; 4 ct-siblings of one rt adjacent
    const int logical = ((int)blockIdx.x & 7) * 64 + ((int)blockIdx.x >> 3);
    const int rt = logical >> 2;
    const int ct = logical & 3;

    const int tid = threadIdx.x;
    const int l15 = tid & 15;
    const int l4  = (tid >> 4) & 3;
    const int wv  = tid >> 6;        // 0..7
    const int wm  = wv >> 2;         // 0..1  (128 rows each)
    const int wn  = wv & 3;          // 0..3  (64 cols each)

    __shared__ char lds[98304];      // A 3x16KB + B 3x16KB
    __shared__ float red[4][256];

    const int rowbase = rt * 256;
    const char* bT = (const char*)weT + ((size_t)ct << 20);

    // ---- A staging: thread -> row ar=tid>>1, k-half ah=tid&1 (16 floats) ----
    const int ar_ = tid >> 1;
    const int ah  = tid & 1;
    const float* aG = enc + (size_t)(rowbase + ar_) * KDIM + ah * 16;
    const int aswz = (ar_ >> 1) & 3;
    const int awb0 = ar_ * 64 + (((2 * ah)     ^ aswz) << 4);
    const int awb1 = ar_ * 64 + (((2 * ah + 1) ^ aswz) << 4);

    // ---- frag reads (r5-verified 0-conflict): row 64B, phys = l4^((row>>1)&3)
    const int fswz = (l4 ^ ((l15 >> 1) & 3)) << 4;
    const int aro = (wm * 128 + l15) * 64 + fswz;   // + i*1024, i=0..7
    const int bro = (wn * 64  + l15) * 64 + fswz;   // + j*1024, j=0..3

    f32x4 acc[8][4] = {};

    auto loadAreg = [&](float4 (&s)[4], int t) {
        const float* p = aG + (size_t)t * 32;
        s[0] = *(const float4*)(p);
        s[1] = *(const float4*)(p + 4);
        s[2] = *(const float4*)(p + 8);
        s[3] = *(const float4*)(p + 12);
    };
    auto writeA = [&](const float4 (&s)[4], int slot) {
        char* d = lds + A_OFF(slot);
        auto c0 = __builtin_amdgcn_cvt_pkrtz(s[0].x, s[0].y);
        auto c1 = __builtin_amdgcn_cvt_pkrtz(s[0].z, s[0].w);
        auto c2 = __builtin_amdgcn_cvt_pkrtz(s[1].x, s[1].y);
        auto c3 = __builtin_amdgcn_cvt_pkrtz(s[1].z, s[1].w);
        auto c4 = __builtin_amdgcn_cvt_pkrtz(s[2].x, s[2].y);
        auto c5 = __builtin_amdgcn_cvt_pkrtz(s[2].z, s[2].w);
        auto c6 = __builtin_amdgcn_cvt_pkrtz(s[3].x, s[3].y);
        auto c7 = __builtin_amdgcn_cvt_pkrtz(s[3].z, s[3].w);
        f16x8 h0 = { (f16)c0[0],(f16)c0[1],(f16)c1[0],(f16)c1[1],
                     (f16)c2[0],(f16)c2[1],(f16)c3[0],(f16)c3[1] };
        f16x8 h1 = { (f16)c4[0],(f16)c4[1],(f16)c5[0],(f16)c5[1],
                     (f16)c6[0],(f16)c6[1],(f16)c7[0],(f16)c7[1] };
        *(f16x8*)(d + awb0) = h0;
        *(f16x8*)(d + awb1) = h1;
    };
    auto stageB = [&](int t, int slot) {
        const char* s = bT + ((size_t)t << 14) + tid * 16;
        char* d = lds + B_OFF(slot) + tid * 16;
        gload16(s, d); gload16(s + 8192, d + 8192);
    };

    // ---- prologue: A tiles 0,1 cvt->slots 0,1; B tiles 0,1 -> slots 0,1 ----
    {
        float4 s0[4];
        loadAreg(s0, 0);
        writeA(s0, 0);            // auto-vmcnt waits A(0) loads
        loadAreg(s0, 1);
        writeA(s0, 1);            // waits A(1)
        stageB(0, 0); stageB(1, 1);
        asm volatile("s_waitcnt lgkmcnt(0)" ::: "memory");   // A writes drained
        asm volatile("s_waitcnt vmcnt(2)" ::: "memory");     // B(0) landed; B(1) in flight
        __builtin_amdgcn_s_barrier();
        __builtin_amdgcn_sched_barrier(0);
    }

    int rS = 0, wS = 2;   // read slot t%3, write slot (t+2)%3
    #pragma unroll 1
    for (int t = 0; t < NKT; ++t) {
        const bool pre = (t + 2 < NKT);
        float4 sS[4];
        if (pre) loadAreg(sS, t + 2);          // issue early: max cover
        const char* sa = lds + A_OFF(rS);
        const char* sb = lds + B_OFF(rS);
        f16x8 fa[8], bf[4];
        #pragma unroll
        for (int ii = 0; ii < 8; ++ii) fa[ii] = *(const f16x8*)(sa + aro + ii * 1024);
        #pragma unroll
        for (int j = 0; j < 4; ++j)  bf[j]  = *(const f16x8*)(sb + bro + j * 1024);
        __builtin_amdgcn_sched_barrier(0);
        // MFMA group 1 (i=0..5): granular lgkm — trailing reads drain underneath
        __builtin_amdgcn_s_setprio(1);
        #pragma unroll
        for (int ii = 0; ii < 6; ++ii)
            #pragma unroll
            for (int j = 0; j < 4; ++j)
                acc[ii][j] = __builtin_amdgcn_mfma_f32_16x16x32_f16(fa[ii], bf[j], acc[ii][j], 0, 0, 0);
        __builtin_amdgcn_s_setprio(0);
        __builtin_amdgcn_sched_barrier(0);
        if (pre) {
            writeA(sS, wS);                    // auto-vmcnt: stalls only this wave
            stageB(t + 2, wS);
        }
        __builtin_amdgcn_sched_barrier(0);
        // MFMA group 2 (i=6..7)
        __builtin_amdgcn_s_setprio(1);
        #pragma unroll
        for (int ii = 6; ii < 8; ++ii)
            #pragma unroll
            for (int j = 0; j < 4; ++j)
                acc[ii][j] = __builtin_amdgcn_mfma_f32_16x16x32_f16(fa[ii], bf[j], acc[ii][j], 0, 0, 0);
        __builtin_amdgcn_s_setprio(0);
        asm volatile("s_waitcnt lgkmcnt(0)" ::: "memory");   // drain own ds_writes
        if (t < NKT - 2) { asm volatile("s_waitcnt vmcnt(2)" ::: "memory"); }  // B(t+1) landed, B(t+2) in flight
        else             { asm volatile("s_waitcnt vmcnt(0)" ::: "memory"); }
        __builtin_amdgcn_s_barrier();
        __builtin_amdgcn_sched_barrier(0);
        rS = (rS == 2) ? 0 : rS + 1;
        wS = (wS == 2) ? 0 : wS + 1;
    }

    // ---------------- epilogue ----------------
    // C/D frag: col = l15, row = l4*4 + q; global row = rowbase + wm*128 + i*16 + l4*4 + q
    const int colbase = ct * 256;
    const int bidx = rt >> 3;

    float sd[4], vs[4];
    #pragma unroll
    for (int j = 0; j < 4; ++j) {
        const int col = colbase + wn * 64 + j * 16 + l15;
        sd[j] = sdec[bidx * 1024 + col];
        vs[j] = vw[col];
    }
    float psum[8][4] = {};
    #pragma unroll
    for (int i = 0; i < 8; ++i)
        #pragma unroll
        for (int j = 0; j < 4; ++j)
            #pragma unroll
            for (int q = 0; q < 4; ++q)
                psum[i][q] += tanh_mul(acc[i][j][q] + sd[j], vs[j]);

    #pragma unroll
    for (int i = 0; i < 8; ++i)
        #pragma unroll
        for (int q = 0; q < 4; ++q) {
            float s = psum[i][q];
            s += __shfl_xor(s, 1); s += __shfl_xor(s, 2);
            s += __shfl_xor(s, 4); s += __shfl_xor(s, 8);
            psum[i][q] = s;
        }

    __syncthreads();
    if (l15 == 0) {
        #pragma unroll
        for (int i = 0; i < 8; ++i)
            #pragma unroll
            for (int q = 0; q < 4; ++q)
                red[wn][wm * 128 + i * 16 + l4 * 4 + q] = psum[i][q];
    }
    __syncthreads();
    if (tid < 256)
        part[(size_t)ct * M_TOT + rowbase + tid] =
            red[0][tid] + red[1][tid] + red[2][tid] + red[3][tid];
}

// softmax over L per batch; mask==0 -> -1e10; sums the NCT partials.
__global__ __launch_bounds__(512) void softmax_kernel(
        const float* __restrict__ part, const int* __restrict__ mask,
        float* __restrict__ out) {
    int b = blockIdx.x;
    int tid = threadIdx.x;
    int lane = tid & 63, w = tid >> 6;
    __shared__ float sred[8];

    float vals[4];
    #pragma unroll
    for (int p = 0; p < 4; ++p) {
        int row = b * LSEQ + tid + p * 512;
        float val = 0.f;
        #pragma unroll
        for (int q = 0; q < NCT; ++q) val += part[(size_t)q * M_TOT + row];
        vals[p] = (mask[row] == 0) ? NEG_INF_F : val;
    }
    float mx = fmaxf(fmaxf(vals[0], vals[1]), fmaxf(vals[2], vals[3]));
    #pragma unroll
    for (int m = 1; m < 64; m <<= 1) mx = fmaxf(mx, __shfl_xor(mx, m));
    if (lane == 0) sred[w] = mx;
    __syncthreads();
    float gmax = sred[0];
    #pragma unroll
    for (int i = 1; i < 8; ++i) gmax = fmaxf(gmax, sred[i]);

    float es[4]; float ssum = 0.f;
    #pragma unroll
    for (int p = 0; p < 4; ++p) { es[p] = expf(vals[p] - gmax); ssum += es[p]; }
    #pragma unroll
    for (int m = 1; m < 64; m <<= 1) ssum += __shfl_xor(ssum, m);
    __syncthreads();
    if (lane == 0) sred[w] = ssum;
    __syncthreads();
    float gsum = 0.f;
    #pragma unroll
    for (int i = 0; i < 8; ++i) gsum += sred[i];
    float inv = 1.f / gsum;
    #pragma unroll
    for (int p = 0; p < 4; ++p)
        out[b * LSEQ + tid + p * 512] = es[p] * inv;
}

extern "C" void kernel_launch(void* const* d_in, const int* in_sizes, int n_in,
                              void* d_out, int out_size, void* d_ws, size_t ws_size,
                              hipStream_t stream) {
    const float* enc    = (const float*)d_in[0];
    const int*   mask   = (const int*)  d_in[1];
    const float* v      = (const float*)d_in[2];
    const float* attn_w = (const float*)d_in[3];
    const float* attn_b = (const float*)d_in[4];
    const float* v_w    = (const float*)d_in[5];
    float* out = (float*)d_out;

    char* ws = (char*)d_ws;
    float* sdec = (float*)(ws + WS_SDEC_OFF);
    float* part = (float*)(ws + WS_PART_OFF);
    f16*   weT  = (f16*)  (ws + WS_WET_OFF);

    hipLaunchKernelGGL(wecvt_tiled, dim3(256),  dim3(256), 0, stream, attn_w, weT);
    hipLaunchKernelGGL(sdec_kernel, dim3(4096), dim3(256), 0, stream, v, attn_w, attn_b, sdec);
    hipLaunchKernelGGL(fused_gemm,  dim3(512),  dim3(512), 0, stream,
                       enc, weT, sdec, v_w, part);
    hipLaunchKernelGGL(softmax_kernel, dim3(16), dim3(512), 0, stream, part, mask, out);
}

// Round 17
// 178.397 us; speedup vs baseline: 2.7755x; 1.2073x over previous
//
#include <hip/hip_runtime.h>
#include <stdint.h>

#define LSEQ 2048
#define M_TOT 32768          // B*L
#define KDIM 2048            // 2H
#define NKT 64               // K tiles of 32
#define NCT 4                // col tiles of 256
#define NEG_INF_F (-10000000000.0f)

typedef _Float16 f16;
typedef f16 f16x8 __attribute__((ext_vector_type(8)));
typedef float f32x4 __attribute__((ext_vector_type(4)));

// ---------------- ws layout ----------------
// [0, 64K)      sdec f32[16][1024]
// [64K, 576K)   part f32[4][32768]
// [2M, 6M)      weT  tiled fp16 B [4 ct][64 kt][1024 granules x 16B]
#define WS_SDEC_OFF  0
#define WS_PART_OFF  (64u << 10)
#define WS_WET_OFF   (2u << 20)

// LDS: A 2 slots x 8KB + B 3 slots x 16KB = 64KB  -> 2 blocks/CU
#define A_OFF(s) ((s) * 8192)
#define B_OFF(s) (16384 + (s) * 16384)

__device__ inline void gload16(const void* g, void* l) {
    __builtin_amdgcn_global_load_lds(
        (const __attribute__((address_space(1))) void*)g,
        (__attribute__((address_space(3))) void*)l, 16, 0, 0);
}

// fast tanh(x)*s with sign fold
__device__ inline float tanh_mul(float x, float s) {
    float ax = __builtin_fabsf(x);
    float e  = __expf(-2.f * ax);
    float th = (1.f - e) * __builtin_amdgcn_rcpf(1.f + e);
    float sv = __uint_as_float(__float_as_uint(s) ^ (__float_as_uint(x) & 0x80000000u));
    return th * sv;
}

// W_e -> tiled fp16 B, 0-conflict swizzle (r5-verified): granule g: ct=g>>16,
// kt=(g>>10)&63, p=g&1023, row=p>>2, sl=(p&3)^((row>>1)&3).
__global__ __launch_bounds__(256) void wecvt_tiled(const float* __restrict__ attn_w,
                                                   f16* __restrict__ weT) {
    int g = blockIdx.x * 1024 + threadIdx.x;
    #pragma unroll
    for (int q = 0; q < 4; ++q, g += 256) {
        int ct  = g >> 16;
        int rem = g & 65535;
        int kt  = rem >> 10;
        int p   = rem & 1023;
        int row = p >> 2;
        int sl  = (p & 3) ^ ((row >> 1) & 3);
        const float* s = attn_w + (size_t)(ct * 256 + row) * 3072 + 1024 + kt * 32 + sl * 8;
        float4 a = *(const float4*)s;
        float4 b = *(const float4*)(s + 4);
        f16x8 h = { (f16)a.x,(f16)a.y,(f16)a.z,(f16)a.w,(f16)b.x,(f16)b.y,(f16)b.z,(f16)b.w };
        *(f16x8*)(weT + (size_t)g * 8) = h;
    }
}

// score_dec[b][h] = attn_b[h] + sum_k v[b][k] * attn_w[h][k]
__global__ void sdec_kernel(const float* __restrict__ v,
                            const float* __restrict__ attn_w,
                            const float* __restrict__ attn_b,
                            float* __restrict__ sdec) {
    int gid  = blockIdx.x * 4 + (threadIdx.x >> 6);
    int lane = threadIdx.x & 63;
    int b = gid >> 10;
    int h = gid & 1023;
    const float* vr = v + b * 1024;
    const float* wr = attn_w + (size_t)h * 3072;
    float s = 0.f;
    #pragma unroll 4
    for (int k = lane; k < 1024; k += 64) s += vr[k] * wr[k];
    #pragma unroll
    for (int m = 1; m < 64; m <<= 1) s += __shfl_xor(s, m);
    if (lane == 0) sdec[b * 1024 + h] = s + attn_b[h];
}

#define PH_OPEN  do { __builtin_amdgcn_sched_barrier(0); __builtin_amdgcn_s_barrier(); \
                      asm volatile("s_waitcnt lgkmcnt(0)" ::: "memory"); \
                      __builtin_amdgcn_sched_barrier(0); } while (0)
#define PH_CLOSE do { __builtin_amdgcn_sched_barrier(0); __builtin_amdgcn_s_barrier(); } while (0)

// ONE-PASS GEMM, r14 template at HALF BLOCK: 128x256 tile, 4 waves (2M x 2N),
// BK=32, LDS 64KB -> 2 INDEPENDENT blocks/CU (cross-block pipe overlap).
// A: fp32 global -> regs (issued 1 full iteration early) -> cvt_pkrtz ->
//    swizzled ds_write into 2-slot f16 ring.
// B: pre-tiled weT f16 via gload_lds, 3-slot ring, counted vmcnt(8).
// 2 phases/K-tile {ds_reads || issue/cvt/write; BAR; lgkm0; 16 MFMA; BAR}.
__global__ __launch_bounds__(256, 2) void fused_gemm(
        const float* __restrict__ enc,  // [32768][2048] fp32
        const f16* __restrict__ weT,    // [4 ct][64 kt][16KB]
        const float* __restrict__ sdec, // [16][1024]
        const float* __restrict__ vw,   // [1024]
        float* __restrict__ part)       // [NCT][32768]
{
    // chunked XCD remap: 1024 blocks, 128/XCD; 4 ct-siblings of one rt adjacent
    const int logical = ((int)blockIdx.x & 7) * 128 + ((int)blockIdx.x >> 3);
    const int rt = logical >> 2;     // 0..255 (128-row tile)
    const int ct = logical & 3;      // 0..3   (256-col tile)

    const int tid = threadIdx.x;
    const int l15 = tid & 15;
    const int l4  = (tid >> 4) & 3;
    const int wv  = tid >> 6;        // 0..3
    const int wm  = wv >> 1;         // 0..1  (64 rows each)
    const int wn  = wv & 1;          // 0..1  (128 cols each)

    __shared__ char lds[65536];      // A 2x8KB + B 3x16KB
    __shared__ float red[2][128];

    const int rowbase = rt * 128;
    const char* bT = (const char*)weT + ((size_t)ct << 20);

    // ---- A staging: thread -> row ar=tid>>1 (0..127), k-half ah=tid&1 ----
    const int ar_ = tid >> 1;
    const int ah  = tid & 1;
    const float* aG = enc + (size_t)(rowbase + ar_) * KDIM + ah * 16;
    const int aswz = (ar_ >> 1) & 3;
    const int awb0 = ar_ * 64 + (((2 * ah)     ^ aswz) << 4);
    const int awb1 = ar_ * 64 + (((2 * ah + 1) ^ aswz) << 4);

    // ---- frag reads (r5-verified 0-conflict): row 64B, phys = l4^((row>>1)&3)
    const int fswz = (l4 ^ ((l15 >> 1) & 3)) << 4;
    const int aro = (wm * 64  + l15) * 64 + fswz;   // + i*1024, i=0..3
    const int bro = (wn * 128 + l15) * 64 + fswz;   // + j*1024, j=0..7

    f32x4 acc[4][8] = {};

    auto loadAreg = [&](float4 (&s)[4], int t) {
        const float* p = aG + (size_t)t * 32;
        s[0] = *(const float4*)(p);
        s[1] = *(const float4*)(p + 4);
        s[2] = *(const float4*)(p + 8);
        s[3] = *(const float4*)(p + 12);
    };
    auto writeA = [&](const float4 (&s)[4], int slot) {
        char* d = lds + A_OFF(slot);
        auto c0 = __builtin_amdgcn_cvt_pkrtz(s[0].x, s[0].y);
        auto c1 = __builtin_amdgcn_cvt_pkrtz(s[0].z, s[0].w);
        auto c2 = __builtin_amdgcn_cvt_pkrtz(s[1].x, s[1].y);
        auto c3 = __builtin_amdgcn_cvt_pkrtz(s[1].z, s[1].w);
        auto c4 = __builtin_amdgcn_cvt_pkrtz(s[2].x, s[2].y);
        auto c5 = __builtin_amdgcn_cvt_pkrtz(s[2].z, s[2].w);
        auto c6 = __builtin_amdgcn_cvt_pkrtz(s[3].x, s[3].y);
        auto c7 = __builtin_amdgcn_cvt_pkrtz(s[3].z, s[3].w);
        f16x8 h0 = { (f16)c0[0],(f16)c0[1],(f16)c1[0],(f16)c1[1],
                     (f16)c2[0],(f16)c2[1],(f16)c3[0],(f16)c3[1] };
        f16x8 h1 = { (f16)c4[0],(f16)c4[1],(f16)c5[0],(f16)c5[1],
                     (f16)c6[0],(f16)c6[1],(f16)c7[0],(f16)c7[1] };
        *(f16x8*)(d + awb0) = h0;
        *(f16x8*)(d + awb1) = h1;
    };
    auto stageB = [&](int t, int slot) {
        const char* s = bT + ((size_t)t << 14) + tid * 16;
        char* d = lds + B_OFF(slot) + tid * 16;
        gload16(s, d);           gload16(s + 4096, d + 4096);
        gload16(s + 8192, d + 8192); gload16(s + 12288, d + 12288);
    };

    int brS = 0, bwS = 2;

    auto body = [&](int t, float4 (&sIss)[4], float4 (&sCvt)[4]) {
        const char* sa = lds + A_OFF(t & 1);
        const char* sb = lds + B_OFF(brS);
        f16x8 fa[4], bf[4];
        // ---------- phase 0: all A frags + B j=0..3 ----------
        #pragma unroll
        for (int ii = 0; ii < 4; ++ii) fa[ii] = *(const f16x8*)(sa + aro + ii * 1024);
        #pragma unroll
        for (int j = 0; j < 4; ++j)  bf[j]  = *(const f16x8*)(sb + bro + j * 1024);
        if (t + 2 < NKT) loadAreg(sIss, t + 2);
        PH_OPEN;
        __builtin_amdgcn_s_setprio(1);
        #pragma unroll
        for (int ii = 0; ii < 4; ++ii)
            #pragma unroll
            for (int j = 0; j < 4; ++j)
                acc[ii][j] = __builtin_amdgcn_mfma_f32_16x16x32_f16(fa[ii], bf[j], acc[ii][j], 0, 0, 0);
        __builtin_amdgcn_s_setprio(0);
        PH_CLOSE;
        // ---------- phase 1: B j=4..7 ----------
        #pragma unroll
        for (int j = 0; j < 4; ++j) bf[j] = *(const f16x8*)(sb + bro + (4 + j) * 1024);
        if (t + 1 < NKT) writeA(sCvt, (t + 1) & 1);   // regs issued 1 iter ago
        if (t + 2 < NKT) stageB(t + 2, bwS);
        PH_OPEN;
        __builtin_amdgcn_s_setprio(1);
        #pragma unroll
        for (int ii = 0; ii < 4; ++ii)
            #pragma unroll
            for (int j = 0; j < 4; ++j)
                acc[ii][4 + j] = __builtin_amdgcn_mfma_f32_16x16x32_f16(fa[ii], bf[j], acc[ii][4 + j], 0, 0, 0);
        __builtin_amdgcn_s_setprio(0);
        // counted vmcnt: stB(t+1) (issued iter t-1) must be landed for next iter;
        // leaves ldA(t+2) 4 + stB(t+2) 4 in flight.
        if (t < NKT - 2) { asm volatile("s_waitcnt vmcnt(8)" ::: "memory"); }
        else             { asm volatile("s_waitcnt vmcnt(0)" ::: "memory"); }
        PH_CLOSE;
        brS = (brS == 2) ? 0 : brS + 1;
        bwS = (bwS == 2) ? 0 : bwS + 1;
    };

    float4 sEven[4], sOdd[4];
    // ---- prologue: A(0) -> slot0 (direct), A(1) -> regs (held), B(0),B(1) ----
    loadAreg(sEven, 0);
    writeA(sEven, 0);                 // auto-vmcnt waits A(0) loads
    loadAreg(sOdd, 1);                // consumed at iter 0 phase 1 -> slot 1
    stageB(0, 0); stageB(1, 1);
    asm volatile("s_waitcnt lgkmcnt(0)" ::: "memory");   // A(0) ds_writes drained
    asm volatile("s_waitcnt vmcnt(4)" ::: "memory");     // B(0) landed; B(1) in flight
    __builtin_amdgcn_s_barrier();
    __builtin_amdgcn_sched_barrier(0);

    #pragma unroll 1
    for (int tt = 0; tt < NKT; tt += 2) {
        body(tt,     sEven, sOdd);    // issues A(tt+2)->sEven, cvt sOdd -> tile tt+1
        body(tt + 1, sOdd,  sEven);   // issues A(tt+3)->sOdd,  cvt sEven -> tile tt+2
    }

    // ---------------- epilogue ----------------
    // C/D frag: col = l15, row = l4*4 + q; global row = rowbase + wm*64 + i*16 + l4*4 + q
    const int colbase = ct * 256;
    const int bidx = rt >> 4;         // 128-row tiles, 16 per batch

    float sd[8], vs[8];
    #pragma unroll
    for (int j = 0; j < 8; ++j) {
        const int col = colbase + wn * 128 + j * 16 + l15;
        sd[j] = sdec[bidx * 1024 + col];
        vs[j] = vw[col];
    }
    float psum[4][4] = {};
    #pragma unroll
    for (int i = 0; i < 4; ++i)
        #pragma unroll
        for (int j = 0; j < 8; ++j)
            #pragma unroll
            for (int q = 0; q < 4; ++q)
                psum[i][q] += tanh_mul(acc[i][j][q] + sd[j], vs[j]);

    #pragma unroll
    for (int i = 0; i < 4; ++i)
        #pragma unroll
        for (int q = 0; q < 4; ++q) {
            float s = psum[i][q];
            s += __shfl_xor(s, 1); s += __shfl_xor(s, 2);
            s += __shfl_xor(s, 4); s += __shfl_xor(s, 8);
            psum[i][q] = s;
        }

    __syncthreads();
    if (l15 == 0) {
        #pragma unroll
        for (int i = 0; i < 4; ++i)
            #pragma unroll
            for (int q = 0; q < 4; ++q)
                red[wn][wm * 64 + i * 16 + l4 * 4 + q] = psum[i][q];
    }
    __syncthreads();
    if (tid < 128)
        part[(size_t)ct * M_TOT + rowbase + tid] = red[0][tid] + red[1][tid];
}

// softmax over L per batch; mask==0 -> -1e10; sums the NCT partials.
__global__ __launch_bounds__(512) void softmax_kernel(
        const float* __restrict__ part, const int* __restrict__ mask,
        float* __restrict__ out) {
    int b = blockIdx.x;
    int tid = threadIdx.x;
    int lane = tid & 63, w = tid >> 6;
    __shared__ float sred[8];

    float vals[4];
    #pragma unroll
    for (int p = 0; p < 4; ++p) {
        int row = b * LSEQ + tid + p * 512;
        float val = 0.f;
        #pragma unroll
        for (int q = 0; q < NCT; ++q) val += part[(size_t)q * M_TOT + row];
        vals[p] = (mask[row] == 0) ? NEG_INF_F : val;
    }
    float mx = fmaxf(fmaxf(vals[0], vals[1]), fmaxf(vals[2], vals[3]));
    #pragma unroll
    for (int m = 1; m < 64; m <<= 1) mx = fmaxf(mx, __shfl_xor(mx, m));
    if (lane == 0) sred[w] = mx;
    __syncthreads();
    float gmax = sred[0];
    #pragma unroll
    for (int i = 1; i < 8; ++i) gmax = fmaxf(gmax, sred[i]);

    float es[4]; float ssum = 0.f;
    #pragma unroll
    for (int p = 0; p < 4; ++p) { es[p] = expf(vals[p] - gmax); ssum += es[p]; }
    #pragma unroll
    for (int m = 1; m < 64; m <<= 1) ssum += __shfl_xor(ssum, m);
    __syncthreads();
    if (lane == 0) sred[w] = ssum;
    __syncthreads();
    float gsum = 0.f;
    #pragma unroll
    for (int i = 0; i < 8; ++i) gsum += sred[i];
    float inv = 1.f / gsum;
    #pragma unroll
    for (int p = 0; p < 4; ++p)
        out[b * LSEQ + tid + p * 512] = es[p] * inv;
}

extern "C" void kernel_launch(void* const* d_in, const int* in_sizes, int n_in,
                              void* d_out, int out_size, void* d_ws, size_t ws_size,
                              hipStream_t stream) {
    const float* enc    = (const float*)d_in[0];
    const int*   mask   = (const int*)  d_in[1];
    const float* v      = (const float*)d_in[2];
    const float* attn_w = (const float*)d_in[3];
    const float* attn_b = (const float*)d_in[4];
    const float* v_w    = (const float*)d_in[5];
    float* out = (float*)d_out;

    char* ws = (char*)d_ws;
    float* sdec = (float*)(ws + WS_SDEC_OFF);
    float* part = (float*)(ws + WS_PART_OFF);
    f16*   weT  = (f16*)  (ws + WS_WET_OFF);

    hipLaunchKernelGGL(wecvt_tiled, dim3(256),  dim3(256), 0, stream, attn_w, weT);
    hipLaunchKernelGGL(sdec_kernel, dim3(4096), dim3(256), 0, stream, v, attn_w, attn_b, sdec);
    hipLaunchKernelGGL(fused_gemm,  dim3(1024), dim3(256), 0, stream,
                       enc, weT, sdec, v_w, part);
    hipLaunchKernelGGL(softmax_kernel, dim3(16), dim3(512), 0, stream, part, mask, out);
}

// Round 18
// 138.117 us; speedup vs baseline: 3.5849x; 1.2916x over previous
//
#include <hip/hip_runtime.h>
#include <stdint.h>

#define LSEQ 2048
#define M_TOT 32768          // B*L
#define KDIM 2048            // 2H
#define NKT 64               // K tiles of 32
#define NCT 4                // col tiles of 256
#define NEG_INF_F (-10000000000.0f)

typedef _Float16 f16;
typedef f16 f16x8 __attribute__((ext_vector_type(8)));
typedef float f32x4 __attribute__((ext_vector_type(4)));

// ---------------- ws layout ----------------
// [0, 64K)       sdec f32[16][1024]
// [64K, 576K)    part f32[4][32768]
// [576K, 704K)   pos  int[32768]
// [704K, 832K)   ridx int[32768]
// [832K, 833K)   nkeep int[16]
// [2M, 6M)       weT  tiled fp16 B [4 ct][64 kt][1024 granules x 16B]
#define WS_SDEC_OFF  0
#define WS_PART_OFF  (64u << 10)
#define WS_POS_OFF   (576u << 10)
#define WS_RIDX_OFF  (704u << 10)
#define WS_NKEEP_OFF (832u << 10)
#define WS_WET_OFF   (2u << 20)

// LDS: A 2 slots x 8KB + B 3 slots x 16KB = 64KB  -> 2 blocks/CU
#define A_OFF(s) ((s) * 8192)
#define B_OFF(s) (16384 + (s) * 16384)

__device__ inline void gload16(const void* g, void* l) {
    __builtin_amdgcn_global_load_lds(
        (const __attribute__((address_space(1))) void*)g,
        (__attribute__((address_space(3))) void*)l, 16, 0, 0);
}

// fast tanh(x)*s with sign fold
__device__ inline float tanh_mul(float x, float s) {
    float ax = __builtin_fabsf(x);
    float e  = __expf(-2.f * ax);
    float th = (1.f - e) * __builtin_amdgcn_rcpf(1.f + e);
    float sv = __uint_as_float(__float_as_uint(s) ^ (__float_as_uint(x) & 0x80000000u));
    return th * sv;
}

// W_e -> tiled fp16 B, 0-conflict swizzle (r5-verified).
__global__ __launch_bounds__(256) void wecvt_tiled(const float* __restrict__ attn_w,
                                                   f16* __restrict__ weT) {
    int g = blockIdx.x * 1024 + threadIdx.x;
    #pragma unroll
    for (int q = 0; q < 4; ++q, g += 256) {
        int ct  = g >> 16;
        int rem = g & 65535;
        int kt  = rem >> 10;
        int p   = rem & 1023;
        int row = p >> 2;
        int sl  = (p & 3) ^ ((row >> 1) & 3);
        const float* s = attn_w + (size_t)(ct * 256 + row) * 3072 + 1024 + kt * 32 + sl * 8;
        float4 a = *(const float4*)s;
        float4 b = *(const float4*)(s + 4);
        f16x8 h = { (f16)a.x,(f16)a.y,(f16)a.z,(f16)a.w,(f16)b.x,(f16)b.y,(f16)b.z,(f16)b.w };
        *(f16x8*)(weT + (size_t)g * 8) = h;
    }
}

// score_dec[b][h] = attn_b[h] + sum_k v[b][k] * attn_w[h][k]
__global__ void sdec_kernel(const float* __restrict__ v,
                            const float* __restrict__ attn_w,
                            const float* __restrict__ attn_b,
                            float* __restrict__ sdec) {
    int gid  = blockIdx.x * 4 + (threadIdx.x >> 6);
    int lane = threadIdx.x & 63;
    int b = gid >> 10;
    int h = gid & 1023;
    const float* vr = v + b * 1024;
    const float* wr = attn_w + (size_t)h * 3072;
    float s = 0.f;
    #pragma unroll 4
    for (int k = lane; k < 1024; k += 64) s += vr[k] * wr[k];
    #pragma unroll
    for (int m = 1; m < 64; m <<= 1) s += __shfl_xor(s, m);
    if (lane == 0) sdec[b * 1024 + h] = s + attn_b[h];
}

// Per-batch row compaction: prefix-sum over mask!=0. One block per batch,
// 512 threads x 4 rows. ridx[b*2048+p] = global row; pos[row] = p or -1.
__global__ __launch_bounds__(512) void compact_kernel(
        const int* __restrict__ mask, int* __restrict__ ridx,
        int* __restrict__ pos, int* __restrict__ nkeep) {
    int b = blockIdx.x, tid = threadIdx.x;
    int lane = tid & 63, w = tid >> 6;
    __shared__ int wsum[8];
    int base = b * 2048 + tid * 4;
    int m0 = mask[base] != 0, m1 = mask[base + 1] != 0;
    int m2 = mask[base + 2] != 0, m3 = mask[base + 3] != 0;
    int cnt = m0 + m1 + m2 + m3;
    int inc = cnt;
    #pragma unroll
    for (int d = 1; d < 64; d <<= 1) {
        int v = __shfl_up(inc, d);
        if (lane >= d) inc += v;
    }
    if (lane == 63) wsum[w] = inc;
    __syncthreads();
    int wbase = 0, total = 0;
    #pragma unroll
    for (int i = 0; i < 8; ++i) { if (i < w) wbase += wsum[i]; total += wsum[i]; }
    int p = wbase + inc - cnt;   // exclusive prefix
    if (m0) { ridx[b * 2048 + p] = base;     pos[base]     = p; p++; } else pos[base]     = -1;
    if (m1) { ridx[b * 2048 + p] = base + 1; pos[base + 1] = p; p++; } else pos[base + 1] = -1;
    if (m2) { ridx[b * 2048 + p] = base + 2; pos[base + 2] = p; p++; } else pos[base + 2] = -1;
    if (m3) { ridx[b * 2048 + p] = base + 3; pos[base + 3] = p; p++; } else pos[base + 3] = -1;
    if (tid == 0) nkeep[b] = total;
}

#define PH_OPEN  do { __builtin_amdgcn_sched_barrier(0); __builtin_amdgcn_s_barrier(); \
                      asm volatile("s_waitcnt lgkmcnt(0)" ::: "memory"); \
                      __builtin_amdgcn_sched_barrier(0); } while (0)
#define PH_CLOSE do { __builtin_amdgcn_sched_barrier(0); __builtin_amdgcn_s_barrier(); } while (0)

// ONE-PASS GEMM on COMPACTED rows (r17 template): 128x256 tile, 4 waves,
// BK=32, LDS 64KB -> 2 blocks/CU. Tiles past nkeep[b] exit immediately.
// A rows gathered via ridx (row-granular staging -> gather is free).
__global__ __launch_bounds__(256, 2) void fused_gemm(
        const float* __restrict__ enc,  // [32768][2048] fp32
        const f16* __restrict__ weT,    // [4 ct][64 kt][16KB]
        const float* __restrict__ sdec, // [16][1024]
        const float* __restrict__ vw,   // [1024]
        const int* __restrict__ ridx,   // [32768]
        const int* __restrict__ nkeep,  // [16]
        float* __restrict__ part)       // [NCT][32768] (compacted rows)
{
    // chunked XCD remap: 1024 blocks, 128/XCD; 4 ct-siblings of one rt adjacent
    const int logical = ((int)blockIdx.x & 7) * 128 + ((int)blockIdx.x >> 3);
    const int rt = logical >> 2;     // 0..255
    const int ct = logical & 3;

    const int b  = rt >> 4;          // batch
    const int rl = rt & 15;          // tile within batch (128 compacted rows)
    const int nk = nkeep[b];
    if (rl * 128 >= nk) return;      // uniform early exit (before any barrier)

    const int tid = threadIdx.x;
    const int l15 = tid & 15;
    const int l4  = (tid >> 4) & 3;
    const int wv  = tid >> 6;        // 0..3
    const int wm  = wv >> 1;         // 0..1  (64 rows each)
    const int wn  = wv & 1;          // 0..1  (128 cols each)

    __shared__ char lds[65536];      // A 2x8KB + B 3x16KB
    __shared__ float red[2][128];

    const char* bT = (const char*)weT + ((size_t)ct << 20);

    // ---- A staging (gathered): thread -> compacted row rl*128 + (tid>>1) ----
    const int ar_ = tid >> 1;
    const int ah  = tid & 1;
    int cidx = rl * 128 + ar_;
    if (cidx >= nk) cidx = rl * 128;           // pad: clamp to first row of tile
    const int grow = ridx[b * 2048 + cidx];    // global source row
    const float* aG = enc + (size_t)grow * KDIM + ah * 16;
    const int aswz = (ar_ >> 1) & 3;
    const int awb0 = ar_ * 64 + (((2 * ah)     ^ aswz) << 4);
    const int awb1 = ar_ * 64 + (((2 * ah + 1) ^ aswz) << 4);

    // ---- frag reads (r5-verified 0-conflict): row 64B, phys = l4^((row>>1)&3)
    const int fswz = (l4 ^ ((l15 >> 1) & 3)) << 4;
    const int aro = (wm * 64  + l15) * 64 + fswz;   // + i*1024, i=0..3
    const int bro = (wn * 128 + l15) * 64 + fswz;   // + j*1024, j=0..7

    f32x4 acc[4][8] = {};

    auto loadAreg = [&](float4 (&s)[4], int t) {
        const float* p = aG + (size_t)t * 32;
        s[0] = *(const float4*)(p);
        s[1] = *(const float4*)(p + 4);
        s[2] = *(const float4*)(p + 8);
        s[3] = *(const float4*)(p + 12);
    };
    auto writeA = [&](const float4 (&s)[4], int slot) {
        char* d = lds + A_OFF(slot);
        auto c0 = __builtin_amdgcn_cvt_pkrtz(s[0].x, s[0].y);
        auto c1 = __builtin_amdgcn_cvt_pkrtz(s[0].z, s[0].w);
        auto c2 = __builtin_amdgcn_cvt_pkrtz(s[1].x, s[1].y);
        auto c3 = __builtin_amdgcn_cvt_pkrtz(s[1].z, s[1].w);
        auto c4 = __builtin_amdgcn_cvt_pkrtz(s[2].x, s[2].y);
        auto c5 = __builtin_amdgcn_cvt_pkrtz(s[2].z, s[2].w);
        auto c6 = __builtin_amdgcn_cvt_pkrtz(s[3].x, s[3].y);
        auto c7 = __builtin_amdgcn_cvt_pkrtz(s[3].z, s[3].w);
        f16x8 h0 = { (f16)c0[0],(f16)c0[1],(f16)c1[0],(f16)c1[1],
                     (f16)c2[0],(f16)c2[1],(f16)c3[0],(f16)c3[1] };
        f16x8 h1 = { (f16)c4[0],(f16)c4[1],(f16)c5[0],(f16)c5[1],
                     (f16)c6[0],(f16)c6[1],(f16)c7[0],(f16)c7[1] };
        *(f16x8*)(d + awb0) = h0;
        *(f16x8*)(d + awb1) = h1;
    };
    auto stageB = [&](int t, int slot) {
        const char* s = bT + ((size_t)t << 14) + tid * 16;
        char* d = lds + B_OFF(slot) + tid * 16;
        gload16(s, d);               gload16(s + 4096, d + 4096);
        gload16(s + 8192, d + 8192); gload16(s + 12288, d + 12288);
    };

    int brS = 0, bwS = 2;

    auto body = [&](int t, float4 (&sIss)[4], float4 (&sCvt)[4]) {
        const char* sa = lds + A_OFF(t & 1);
        const char* sb = lds + B_OFF(brS);
        f16x8 fa[4], bf[4];
        // ---------- phase 0: all A frags + B j=0..3 ----------
        #pragma unroll
        for (int ii = 0; ii < 4; ++ii) fa[ii] = *(const f16x8*)(sa + aro + ii * 1024);
        #pragma unroll
        for (int j = 0; j < 4; ++j)  bf[j]  = *(const f16x8*)(sb + bro + j * 1024);
        if (t + 2 < NKT) loadAreg(sIss, t + 2);
        PH_OPEN;
        __builtin_amdgcn_s_setprio(1);
        #pragma unroll
        for (int ii = 0; ii < 4; ++ii)
            #pragma unroll
            for (int j = 0; j < 4; ++j)
                acc[ii][j] = __builtin_amdgcn_mfma_f32_16x16x32_f16(fa[ii], bf[j], acc[ii][j], 0, 0, 0);
        __builtin_amdgcn_s_setprio(0);
        PH_CLOSE;
        // ---------- phase 1: B j=4..7 ----------
        #pragma unroll
        for (int j = 0; j < 4; ++j) bf[j] = *(const f16x8*)(sb + bro + (4 + j) * 1024);
        if (t + 1 < NKT) writeA(sCvt, (t + 1) & 1);   // regs issued 1 iter ago
        if (t + 2 < NKT) stageB(t + 2, bwS);
        PH_OPEN;
        __builtin_amdgcn_s_setprio(1);
        #pragma unroll
        for (int ii = 0; ii < 4; ++ii)
            #pragma unroll
            for (int j = 0; j < 4; ++j)
                acc[ii][4 + j] = __builtin_amdgcn_mfma_f32_16x16x32_f16(fa[ii], bf[j], acc[ii][4 + j], 0, 0, 0);
        __builtin_amdgcn_s_setprio(0);
        if (t < NKT - 2) { asm volatile("s_waitcnt vmcnt(8)" ::: "memory"); }
        else             { asm volatile("s_waitcnt vmcnt(0)" ::: "memory"); }
        PH_CLOSE;
        brS = (brS == 2) ? 0 : brS + 1;
        bwS = (bwS == 2) ? 0 : bwS + 1;
    };

    float4 sEven[4], sOdd[4];
    loadAreg(sEven, 0);
    writeA(sEven, 0);
    loadAreg(sOdd, 1);
    stageB(0, 0); stageB(1, 1);
    asm volatile("s_waitcnt lgkmcnt(0)" ::: "memory");
    asm volatile("s_waitcnt vmcnt(4)" ::: "memory");
    __builtin_amdgcn_s_barrier();
    __builtin_amdgcn_sched_barrier(0);

    #pragma unroll 1
    for (int tt = 0; tt < NKT; tt += 2) {
        body(tt,     sEven, sOdd);
        body(tt + 1, sOdd,  sEven);
    }

    // ---------------- epilogue ----------------
    const int colbase = ct * 256;

    float sd[8], vs[8];
    #pragma unroll
    for (int j = 0; j < 8; ++j) {
        const int col = colbase + wn * 128 + j * 16 + l15;
        sd[j] = sdec[b * 1024 + col];
        vs[j] = vw[col];
    }
    float psum[4][4] = {};
    #pragma unroll
    for (int i = 0; i < 4; ++i)
        #pragma unroll
        for (int j = 0; j < 8; ++j)
            #pragma unroll
            for (int q = 0; q < 4; ++q)
                psum[i][q] += tanh_mul(acc[i][j][q] + sd[j], vs[j]);

    #pragma unroll
    for (int i = 0; i < 4; ++i)
        #pragma unroll
        for (int q = 0; q < 4; ++q) {
            float s = psum[i][q];
            s += __shfl_xor(s, 1); s += __shfl_xor(s, 2);
            s += __shfl_xor(s, 4); s += __shfl_xor(s, 8);
            psum[i][q] = s;
        }

    __syncthreads();
    if (l15 == 0) {
        #pragma unroll
        for (int i = 0; i < 4; ++i)
            #pragma unroll
            for (int q = 0; q < 4; ++q)
                red[wn][wm * 64 + i * 16 + l4 * 4 + q] = psum[i][q];
    }
    __syncthreads();
    if (tid < 128)
        part[(size_t)ct * M_TOT + b * 2048 + rl * 128 + tid] =
            red[0][tid] + red[1][tid];
}

// softmax over L per batch; pos<0 -> -1e10; else sum NCT partials at compacted row.
__global__ __launch_bounds__(512) void softmax_kernel(
        const float* __restrict__ part, const int* __restrict__ pos,
        float* __restrict__ out) {
    int b = blockIdx.x;
    int tid = threadIdx.x;
    int lane = tid & 63, w = tid >> 6;
    __shared__ float sred[8];

    float vals[4];
    #pragma unroll
    for (int p = 0; p < 4; ++p) {
        int row = b * LSEQ + tid + p * 512;
        int pp = pos[row];
        float val = NEG_INF_F;
        if (pp >= 0) {
            int crow = b * 2048 + pp;
            val = 0.f;
            #pragma unroll
            for (int q = 0; q < NCT; ++q) val += part[(size_t)q * M_TOT + crow];
        }
        vals[p] = val;
    }
    float mx = fmaxf(fmaxf(vals[0], vals[1]), fmaxf(vals[2], vals[3]));
    #pragma unroll
    for (int m = 1; m < 64; m <<= 1) mx = fmaxf(mx, __shfl_xor(mx, m));
    if (lane == 0) sred[w] = mx;
    __syncthreads();
    float gmax = sred[0];
    #pragma unroll
    for (int i = 1; i < 8; ++i) gmax = fmaxf(gmax, sred[i]);

    float es[4]; float ssum = 0.f;
    #pragma unroll
    for (int p = 0; p < 4; ++p) { es[p] = expf(vals[p] - gmax); ssum += es[p]; }
    #pragma unroll
    for (int m = 1; m < 64; m <<= 1) ssum += __shfl_xor(ssum, m);
    __syncthreads();
    if (lane == 0) sred[w] = ssum;
    __syncthreads();
    float gsum = 0.f;
    #pragma unroll
    for (int i = 0; i < 8; ++i) gsum += sred[i];
    float inv = 1.f / gsum;
    #pragma unroll
    for (int p = 0; p < 4; ++p)
        out[b * LSEQ + tid + p * 512] = es[p] * inv;
}

extern "C" void kernel_launch(void* const* d_in, const int* in_sizes, int n_in,
                              void* d_out, int out_size, void* d_ws, size_t ws_size,
                              hipStream_t stream) {
    const float* enc    = (const float*)d_in[0];
    const int*   mask   = (const int*)  d_in[1];
    const float* v      = (const float*)d_in[2];
    const float* attn_w = (const float*)d_in[3];
    const float* attn_b = (const float*)d_in[4];
    const float* v_w    = (const float*)d_in[5];
    float* out = (float*)d_out;

    char* ws = (char*)d_ws;
    float* sdec  = (float*)(ws + WS_SDEC_OFF);
    float* part  = (float*)(ws + WS_PART_OFF);
    int*   pos   = (int*)  (ws + WS_POS_OFF);
    int*   ridx  = (int*)  (ws + WS_RIDX_OFF);
    int*   nkeep = (int*)  (ws + WS_NKEEP_OFF);
    f16*   weT   = (f16*)  (ws + WS_WET_OFF);

    hipLaunchKernelGGL(wecvt_tiled,    dim3(256),  dim3(256), 0, stream, attn_w, weT);
    hipLaunchKernelGGL(sdec_kernel,    dim3(4096), dim3(256), 0, stream, v, attn_w, attn_b, sdec);
    hipLaunchKernelGGL(compact_kernel, dim3(16),   dim3(512), 0, stream, mask, ridx, pos, nkeep);
    hipLaunchKernelGGL(fused_gemm,     dim3(1024), dim3(256), 0, stream,
                       enc, weT, sdec, v_w, ridx, nkeep, part);
    hipLaunchKernelGGL(softmax_kernel, dim3(16),   dim3(512), 0, stream, part, pos, out);
}

// Round 19
// 134.174 us; speedup vs baseline: 3.6902x; 1.0294x over previous
//
#include <hip/hip_runtime.h>
#include <stdint.h>

#define LSEQ 2048
#define M_TOT 32768          // B*L
#define KDIM 2048            // 2H
#define NKT 64               // K tiles of 32
#define NCT 4                // col tiles of 256
#define NEG_INF_F (-10000000000.0f)

typedef _Float16 f16;
typedef f16 f16x8 __attribute__((ext_vector_type(8)));
typedef float f32x4 __attribute__((ext_vector_type(4)));

// ---------------- ws layout ----------------
// [0, 64K)       sdec f32[16][1024]
// [64K, 576K)    part f32[4][32768]
// [576K, 704K)   pos  int[32768]
// [704K, 832K)   ridx int[32768]
// [832K, 833K)   nkeep int[16]
// [2M, 6M)       weT  tiled fp16 B [4 ct][64 kt][1024 granules x 16B]
#define WS_SDEC_OFF  0
#define WS_PART_OFF  (64u << 10)
#define WS_POS_OFF   (576u << 10)
#define WS_RIDX_OFF  (704u << 10)
#define WS_NKEEP_OFF (832u << 10)
#define WS_WET_OFF   (2u << 20)

// LDS: A 2 slots x 8KB + B 3 slots x 16KB = 64KB  -> 2 blocks/CU
#define A_OFF(s) ((s) * 8192)
#define B_OFF(s) (16384 + (s) * 16384)

__device__ inline void gload16(const void* g, void* l) {
    __builtin_amdgcn_global_load_lds(
        (const __attribute__((address_space(1))) void*)g,
        (__attribute__((address_space(3))) void*)l, 16, 0, 0);
}

// fast tanh(x)*s with sign fold
__device__ inline float tanh_mul(float x, float s) {
    float ax = __builtin_fabsf(x);
    float e  = __expf(-2.f * ax);
    float th = (1.f - e) * __builtin_amdgcn_rcpf(1.f + e);
    float sv = __uint_as_float(__float_as_uint(s) ^ (__float_as_uint(x) & 0x80000000u));
    return th * sv;
}

// MERGED PREP: blocks [0,256) wecvt | [256,1280) sdec | [1280,1296) compact.
// All three are independent; one launch lets them run concurrently.
__global__ __launch_bounds__(256) void prep_kernel(
        const float* __restrict__ attn_w, f16* __restrict__ weT,
        const float* __restrict__ v, const float* __restrict__ attn_b,
        float* __restrict__ sdec,
        const int* __restrict__ mask, int* __restrict__ ridx,
        int* __restrict__ pos, int* __restrict__ nkeep) {
    const int blk = blockIdx.x;
    const int tid = threadIdx.x;
    __shared__ int wsum[4];

    if (blk < 256) {
        // ---- wecvt: W_e -> tiled fp16 B, r5-verified 0-conflict swizzle ----
        int g = blk * 1024 + tid;
        #pragma unroll
        for (int q = 0; q < 4; ++q, g += 256) {
            int ct  = g >> 16;
            int rem = g & 65535;
            int kt  = rem >> 10;
            int p   = rem & 1023;
            int row = p >> 2;
            int sl  = (p & 3) ^ ((row >> 1) & 3);
            const float* s = attn_w + (size_t)(ct * 256 + row) * 3072 + 1024 + kt * 32 + sl * 8;
            float4 a = *(const float4*)s;
            float4 b = *(const float4*)(s + 4);
            f16x8 h = { (f16)a.x,(f16)a.y,(f16)a.z,(f16)a.w,(f16)b.x,(f16)b.y,(f16)b.z,(f16)b.w };
            *(f16x8*)(weT + (size_t)g * 8) = h;
        }
    } else if (blk < 1280) {
        // ---- sdec: wave handles 4 (b,h) pairs ----
        const int wave = (blk - 256) * 4 + (tid >> 6);
        const int lane = tid & 63;
        #pragma unroll
        for (int i = 0; i < 4; ++i) {
            const int gid = wave * 4 + i;      // 0..16383
            const int b = gid >> 10;
            const int h = gid & 1023;
            const float* vr = v + b * 1024;
            const float* wr = attn_w + (size_t)h * 3072;
            float s = 0.f;
            #pragma unroll 4
            for (int k = lane; k < 1024; k += 64) s += vr[k] * wr[k];
            #pragma unroll
            for (int m = 1; m < 64; m <<= 1) s += __shfl_xor(s, m);
            if (lane == 0) sdec[b * 1024 + h] = s + attn_b[h];
        }
    } else {
        // ---- compact: per-batch prefix sum over mask!=0; 256 thr x 8 rows ----
        const int b = blk - 1280;
        const int lane = tid & 63, w = tid >> 6;
        const int base = b * 2048 + tid * 8;
        int m[8], cnt = 0;
        #pragma unroll
        for (int i = 0; i < 8; ++i) { m[i] = mask[base + i] != 0; cnt += m[i]; }
        int inc = cnt;
        #pragma unroll
        for (int d = 1; d < 64; d <<= 1) {
            int t = __shfl_up(inc, d);
            if (lane >= d) inc += t;
        }
        if (lane == 63) wsum[w] = inc;
        __syncthreads();
        int wbase = 0, total = 0;
        #pragma unroll
        for (int i = 0; i < 4; ++i) { if (i < w) wbase += wsum[i]; total += wsum[i]; }
        int p = wbase + inc - cnt;   // exclusive prefix
        #pragma unroll
        for (int i = 0; i < 8; ++i) {
            if (m[i]) { ridx[b * 2048 + p] = base + i; pos[base + i] = p; p++; }
            else      { pos[base + i] = -1; }
        }
        if (tid == 0) nkeep[b] = total;
    }
}

#define PH_OPEN  do { __builtin_amdgcn_sched_barrier(0); __builtin_amdgcn_s_barrier(); \
                      asm volatile("s_waitcnt lgkmcnt(0)" ::: "memory"); \
                      __builtin_amdgcn_sched_barrier(0); } while (0)
#define PH_CLOSE do { __builtin_amdgcn_sched_barrier(0); __builtin_amdgcn_s_barrier(); } while (0)

// ONE-PASS GEMM on COMPACTED rows (r17 template): 128x256 tile, 4 waves,
// BK=32, LDS 64KB -> 2 blocks/CU. Tiles past nkeep[b] exit immediately.
// A rows gathered via ridx (row-granular staging -> gather is free).
__global__ __launch_bounds__(256, 2) void fused_gemm(
        const float* __restrict__ enc,  // [32768][2048] fp32
        const f16* __restrict__ weT,    // [4 ct][64 kt][16KB]
        const float* __restrict__ sdec, // [16][1024]
        const float* __restrict__ vw,   // [1024]
        const int* __restrict__ ridx,   // [32768]
        const int* __restrict__ nkeep,  // [16]
        float* __restrict__ part)       // [NCT][32768] (compacted rows)
{
    // chunked XCD remap: 1024 blocks, 128/XCD; 4 ct-siblings of one rt adjacent
    const int logical = ((int)blockIdx.x & 7) * 128 + ((int)blockIdx.x >> 3);
    const int rt = logical >> 2;     // 0..255
    const int ct = logical & 3;

    const int b  = rt >> 4;          // batch
    const int rl = rt & 15;          // tile within batch (128 compacted rows)
    const int nk = nkeep[b];
    if (rl * 128 >= nk) return;      // uniform early exit (before any barrier)

    const int tid = threadIdx.x;
    const int l15 = tid & 15;
    const int l4  = (tid >> 4) & 3;
    const int wv  = tid >> 6;        // 0..3
    const int wm  = wv >> 1;         // 0..1  (64 rows each)
    const int wn  = wv & 1;          // 0..1  (128 cols each)

    __shared__ char lds[65536];      // A 2x8KB + B 3x16KB
    __shared__ float red[2][128];

    const char* bT = (const char*)weT + ((size_t)ct << 20);

    // ---- A staging (gathered): thread -> compacted row rl*128 + (tid>>1) ----
    const int ar_ = tid >> 1;
    const int ah  = tid & 1;
    int cidx = rl * 128 + ar_;
    if (cidx >= nk) cidx = rl * 128;           // pad: clamp to first row of tile
    const int grow = ridx[b * 2048 + cidx];    // global source row
    const float* aG = enc + (size_t)grow * KDIM + ah * 16;
    const int aswz = (ar_ >> 1) & 3;
    const int awb0 = ar_ * 64 + (((2 * ah)     ^ aswz) << 4);
    const int awb1 = ar_ * 64 + (((2 * ah + 1) ^ aswz) << 4);

    // ---- frag reads (r5-verified 0-conflict): row 64B, phys = l4^((row>>1)&3)
    const int fswz = (l4 ^ ((l15 >> 1) & 3)) << 4;
    const int aro = (wm * 64  + l15) * 64 + fswz;   // + i*1024, i=0..3
    const int bro = (wn * 128 + l15) * 64 + fswz;   // + j*1024, j=0..7

    f32x4 acc[4][8] = {};

    auto loadAreg = [&](float4 (&s)[4], int t) {
        const float* p = aG + (size_t)t * 32;
        s[0] = *(const float4*)(p);
        s[1] = *(const float4*)(p + 4);
        s[2] = *(const float4*)(p + 8);
        s[3] = *(const float4*)(p + 12);
    };
    auto writeA = [&](const float4 (&s)[4], int slot) {
        char* d = lds + A_OFF(slot);
        auto c0 = __builtin_amdgcn_cvt_pkrtz(s[0].x, s[0].y);
        auto c1 = __builtin_amdgcn_cvt_pkrtz(s[0].z, s[0].w);
        auto c2 = __builtin_amdgcn_cvt_pkrtz(s[1].x, s[1].y);
        auto c3 = __builtin_amdgcn_cvt_pkrtz(s[1].z, s[1].w);
        auto c4 = __builtin_amdgcn_cvt_pkrtz(s[2].x, s[2].y);
        auto c5 = __builtin_amdgcn_cvt_pkrtz(s[2].z, s[2].w);
        auto c6 = __builtin_amdgcn_cvt_pkrtz(s[3].x, s[3].y);
        auto c7 = __builtin_amdgcn_cvt_pkrtz(s[3].z, s[3].w);
        f16x8 h0 = { (f16)c0[0],(f16)c0[1],(f16)c1[0],(f16)c1[1],
                     (f16)c2[0],(f16)c2[1],(f16)c3[0],(f16)c3[1] };
        f16x8 h1 = { (f16)c4[0],(f16)c4[1],(f16)c5[0],(f16)c5[1],
                     (f16)c6[0],(f16)c6[1],(f16)c7[0],(f16)c7[1] };
        *(f16x8*)(d + awb0) = h0;
        *(f16x8*)(d + awb1) = h1;
    };
    auto stageB = [&](int t, int slot) {
        const char* s = bT + ((size_t)t << 14) + tid * 16;
        char* d = lds + B_OFF(slot) + tid * 16;
        gload16(s, d);               gload16(s + 4096, d + 4096);
        gload16(s + 8192, d + 8192); gload16(s + 12288, d + 12288);
    };

    int brS = 0, bwS = 2;

    auto body = [&](int t, float4 (&sIss)[4], float4 (&sCvt)[4]) {
        const char* sa = lds + A_OFF(t & 1);
        const char* sb = lds + B_OFF(brS);
        f16x8 fa[4], bf[4];
        // ---------- phase 0: all A frags + B j=0..3 ----------
        #pragma unroll
        for (int ii = 0; ii < 4; ++ii) fa[ii] = *(const f16x8*)(sa + aro + ii * 1024);
        #pragma unroll
        for (int j = 0; j < 4; ++j)  bf[j]  = *(const f16x8*)(sb + bro + j * 1024);
        if (t + 2 < NKT) loadAreg(sIss, t + 2);
        PH_OPEN;
        __builtin_amdgcn_s_setprio(1);
        #pragma unroll
        for (int ii = 0; ii < 4; ++ii)
            #pragma unroll
            for (int j = 0; j < 4; ++j)
                acc[ii][j] = __builtin_amdgcn_mfma_f32_16x16x32_f16(fa[ii], bf[j], acc[ii][j], 0, 0, 0);
        __builtin_amdgcn_s_setprio(0);
        PH_CLOSE;
        // ---------- phase 1: B j=4..7 ----------
        #pragma unroll
        for (int j = 0; j < 4; ++j) bf[j] = *(const f16x8*)(sb + bro + (4 + j) * 1024);
        if (t + 1 < NKT) writeA(sCvt, (t + 1) & 1);   // regs issued 1 iter ago
        if (t + 2 < NKT) stageB(t + 2, bwS);
        PH_OPEN;
        __builtin_amdgcn_s_setprio(1);
        #pragma unroll
        for (int ii = 0; ii < 4; ++ii)
            #pragma unroll
            for (int j = 0; j < 4; ++j)
                acc[ii][4 + j] = __builtin_amdgcn_mfma_f32_16x16x32_f16(fa[ii], bf[j], acc[ii][4 + j], 0, 0, 0);
        __builtin_amdgcn_s_setprio(0);
        if (t < NKT - 2) { asm volatile("s_waitcnt vmcnt(8)" ::: "memory"); }
        else             { asm volatile("s_waitcnt vmcnt(0)" ::: "memory"); }
        PH_CLOSE;
        brS = (brS == 2) ? 0 : brS + 1;
        bwS = (bwS == 2) ? 0 : bwS + 1;
    };

    float4 sEven[4], sOdd[4];
    loadAreg(sEven, 0);
    writeA(sEven, 0);
    loadAreg(sOdd, 1);
    stageB(0, 0); stageB(1, 1);
    asm volatile("s_waitcnt lgkmcnt(0)" ::: "memory");
    asm volatile("s_waitcnt vmcnt(4)" ::: "memory");
    __builtin_amdgcn_s_barrier();
    __builtin_amdgcn_sched_barrier(0);

    #pragma unroll 1
    for (int tt = 0; tt < NKT; tt += 2) {
        body(tt,     sEven, sOdd);
        body(tt + 1, sOdd,  sEven);
    }

    // ---------------- epilogue ----------------
    const int colbase = ct * 256;

    float sd[8], vs[8];
    #pragma unroll
    for (int j = 0; j < 8; ++j) {
        const int col = colbase + wn * 128 + j * 16 + l15;
        sd[j] = sdec[b * 1024 + col];
        vs[j] = vw[col];
    }
    float psum[4][4] = {};
    #pragma unroll
    for (int i = 0; i < 4; ++i)
        #pragma unroll
        for (int j = 0; j < 8; ++j)
            #pragma unroll
            for (int q = 0; q < 4; ++q)
                psum[i][q] += tanh_mul(acc[i][j][q] + sd[j], vs[j]);

    #pragma unroll
    for (int i = 0; i < 4; ++i)
        #pragma unroll
        for (int q = 0; q < 4; ++q) {
            float s = psum[i][q];
            s += __shfl_xor(s, 1); s += __shfl_xor(s, 2);
            s += __shfl_xor(s, 4); s += __shfl_xor(s, 8);
            psum[i][q] = s;
        }

    __syncthreads();
    if (l15 == 0) {
        #pragma unroll
        for (int i = 0; i < 4; ++i)
            #pragma unroll
            for (int q = 0; q < 4; ++q)
                red[wn][wm * 64 + i * 16 + l4 * 4 + q] = psum[i][q];
    }
    __syncthreads();
    if (tid < 128)
        part[(size_t)ct * M_TOT + b * 2048 + rl * 128 + tid] =
            red[0][tid] + red[1][tid];
}

// softmax over L per batch; pos<0 -> -1e10; else sum NCT partials at compacted row.
__global__ __launch_bounds__(512) void softmax_kernel(
        const float* __restrict__ part, const int* __restrict__ pos,
        float* __restrict__ out) {
    int b = blockIdx.x;
    int tid = threadIdx.x;
    int lane = tid & 63, w = tid >> 6;
    __shared__ float sred[8];

    float vals[4];
    #pragma unroll
    for (int p = 0; p < 4; ++p) {
        int row = b * LSEQ + tid + p * 512;
        int pp = pos[row];
        float val = NEG_INF_F;
        if (pp >= 0) {
            int crow = b * 2048 + pp;
            val = 0.f;
            #pragma unroll
            for (int q = 0; q < NCT; ++q) val += part[(size_t)q * M_TOT + crow];
        }
        vals[p] = val;
    }
    float mx = fmaxf(fmaxf(vals[0], vals[1]), fmaxf(vals[2], vals[3]));
    #pragma unroll
    for (int m = 1; m < 64; m <<= 1) mx = fmaxf(mx, __shfl_xor(mx, m));
    if (lane == 0) sred[w] = mx;
    __syncthreads();
    float gmax = sred[0];
    #pragma unroll
    for (int i = 1; i < 8; ++i) gmax = fmaxf(gmax, sred[i]);

    float es[4]; float ssum = 0.f;
    #pragma unroll
    for (int p = 0; p < 4; ++p) { es[p] = expf(vals[p] - gmax); ssum += es[p]; }
    #pragma unroll
    for (int m = 1; m < 64; m <<= 1) ssum += __shfl_xor(ssum, m);
    __syncthreads();
    if (lane == 0) sred[w] = ssum;
    __syncthreads();
    float gsum = 0.f;
    #pragma unroll
    for (int i = 0; i < 8; ++i) gsum += sred[i];
    float inv = 1.f / gsum;
    #pragma unroll
    for (int p = 0; p < 4; ++p)
        out[b * LSEQ + tid + p * 512] = es[p] * inv;
}

extern "C" void kernel_launch(void* const* d_in, const int* in_sizes, int n_in,
                              void* d_out, int out_size, void* d_ws, size_t ws_size,
                              hipStream_t stream) {
    const float* enc    = (const float*)d_in[0];
    const int*   mask   = (const int*)  d_in[1];
    const float* v      = (const float*)d_in[2];
    const float* attn_w = (const float*)d_in[3];
    const float* attn_b = (const float*)d_in[4];
    const float* v_w    = (const float*)d_in[5];
    float* out = (float*)d_out;

    char* ws = (char*)d_ws;
    float* sdec  = (float*)(ws + WS_SDEC_OFF);
    float* part  = (float*)(ws + WS_PART_OFF);
    int*   pos   = (int*)  (ws + WS_POS_OFF);
    int*   ridx  = (int*)  (ws + WS_RIDX_OFF);
    int*   nkeep = (int*)  (ws + WS_NKEEP_OFF);
    f16*   weT   = (f16*)  (ws + WS_WET_OFF);

    hipLaunchKernelGGL(prep_kernel,    dim3(1296), dim3(256), 0, stream,
                       attn_w, weT, v, attn_b, sdec, mask, ridx, pos, nkeep);
    hipLaunchKernelGGL(fused_gemm,     dim3(1024), dim3(256), 0, stream,
                       enc, weT, sdec, v_w, ridx, nkeep, part);
    hipLaunchKernelGGL(softmax_kernel, dim3(16),   dim3(512), 0, stream, part, pos, out);
}